// Round 1
// baseline (311.724 us; speedup 1.0000x reference)
//
#include <hip/hip_runtime.h>
#include <math.h>

#define WSZ 11
#define PAD 5
#define TX 32
#define TY 32
#define IN_H (TY + 2 * PAD)   // 42
#define IN_W (TX + 2 * PAD)   // 42
#define NTHREADS 256
#define NBLOCKS 2048

struct GW { float g[WSZ]; };

__global__ __launch_bounds__(NTHREADS) void ssim_main_kernel(
    const float* __restrict__ img1, const float* __restrict__ img2,
    float* __restrict__ partials, GW w,
    int planes, int H, int Wd, int tilesX, int tilesY, int nTiles)
{
  __shared__ float s1[IN_H][IN_W];
  __shared__ float s2[IN_H][IN_W];
  __shared__ float sh[5][IN_H][TX];
  __shared__ float sred[NTHREADS / 64];

  const int tid = threadIdx.x;
  float acc = 0.f;

  for (int tile = blockIdx.x; tile < nTiles; tile += gridDim.x) {
    int t = tile;
    const int tx = t % tilesX; t /= tilesX;
    const int ty = t % tilesY; t /= tilesY;
    // t is now the plane index (b*C + c)
    const float* __restrict__ p1 = img1 + (size_t)t * H * Wd;
    const float* __restrict__ p2 = img2 + (size_t)t * H * Wd;
    const int gx0 = tx * TX - PAD;
    const int gy0 = ty * TY - PAD;

    // ---- stage raw tiles (zero-padded at image borders) ----
    for (int i = tid; i < IN_H * IN_W; i += NTHREADS) {
      const int r = i / IN_W, c = i % IN_W;
      const int gy = gy0 + r, gx = gx0 + c;
      const bool ok = (gx >= 0) & (gx < Wd) & (gy >= 0) & (gy < H);
      const size_t idx = (size_t)gy * Wd + gx;
      s1[r][c] = ok ? p1[idx] : 0.f;
      s2[r][c] = ok ? p2[idx] : 0.f;
    }
    __syncthreads();

    // ---- horizontal separable pass over IN_H rows x TX cols ----
    for (int i = tid; i < IN_H * TX; i += NTHREADS) {
      const int r = i / TX, c = i % TX;
      float m1 = 0.f, m2 = 0.f, m11 = 0.f, m22 = 0.f, m12 = 0.f;
#pragma unroll
      for (int k = 0; k < WSZ; k++) {
        const float a = s1[r][c + k];
        const float b = s2[r][c + k];
        const float g = w.g[k];
        m1  += g * a;
        m2  += g * b;
        m11 += g * a * a;
        m22 += g * b * b;
        m12 += g * a * b;
      }
      sh[0][r][c] = m1;
      sh[1][r][c] = m2;
      sh[2][r][c] = m11;
      sh[3][r][c] = m22;
      sh[4][r][c] = m12;
    }
    __syncthreads();

    // ---- vertical pass + SSIM map ----
    for (int i = tid; i < TY * TX; i += NTHREADS) {
      const int r = i / TX, c = i % TX;
      float m1 = 0.f, m2 = 0.f, m11 = 0.f, m22 = 0.f, m12 = 0.f;
#pragma unroll
      for (int k = 0; k < WSZ; k++) {
        const float g = w.g[k];
        m1  += g * sh[0][r + k][c];
        m2  += g * sh[1][r + k][c];
        m11 += g * sh[2][r + k][c];
        m22 += g * sh[3][r + k][c];
        m12 += g * sh[4][r + k][c];
      }
      const float mu1s = m1 * m1;
      const float mu2s = m2 * m2;
      const float mu12 = m1 * m2;
      const float v1q = m11 - mu1s;   // sigma1_sq
      const float v2q = m22 - mu2s;   // sigma2_sq
      const float v12 = m12 - mu12;   // sigma12
      const float C1 = 0.0001f;       // (0.01*L)^2
      const float C2 = 0.0009f;       // (0.03*L)^2
      const float num = (2.f * mu12 + C1) * (2.f * v12 + C2);
      const float den = (mu1s + mu2s + C1) * (v1q + v2q + C2);
      acc += num / den;
    }
    __syncthreads();  // protect LDS before next tile overwrites
  }

  // ---- block reduction: wave shuffle then LDS ----
  for (int off = 32; off > 0; off >>= 1)
    acc += __shfl_down(acc, off, 64);
  if ((tid & 63) == 0) sred[tid >> 6] = acc;
  __syncthreads();
  if (tid == 0) {
    float s = 0.f;
#pragma unroll
    for (int i = 0; i < NTHREADS / 64; i++) s += sred[i];
    partials[blockIdx.x] = s;
  }
}

__global__ __launch_bounds__(NTHREADS) void ssim_final_kernel(
    const float* __restrict__ partials, float* __restrict__ out,
    int n, float invN)
{
  __shared__ float sred[NTHREADS / 64];
  const int tid = threadIdx.x;
  float s = 0.f;
  for (int i = tid; i < n; i += NTHREADS) s += partials[i];
  for (int off = 32; off > 0; off >>= 1)
    s += __shfl_down(s, off, 64);
  if ((tid & 63) == 0) sred[tid >> 6] = s;
  __syncthreads();
  if (tid == 0) {
    float tot = 0.f;
#pragma unroll
    for (int i = 0; i < NTHREADS / 64; i++) tot += sred[i];
    out[0] = 1.f - tot * invN;
  }
}

extern "C" void kernel_launch(void* const* d_in, const int* in_sizes, int n_in,
                              void* d_out, int out_size, void* d_ws, size_t ws_size,
                              hipStream_t stream) {
  const float* img1 = (const float*)d_in[0];
  const float* img2 = (const float*)d_in[1];
  float* out = (float*)d_out;
  float* partials = (float*)d_ws;

  const int H = 512, Wd = 512;
  const int planes = in_sizes[0] / (H * Wd);  // 32*3 = 96
  const int tilesX = (Wd + TX - 1) / TX;      // 16
  const int tilesY = (H + TY - 1) / TY;       // 16
  const int nTiles = planes * tilesX * tilesY; // 24576

  // Gaussian taps, double precision to match numpy, then cast.
  GW w;
  {
    double g[WSZ], sum = 0.0;
    for (int i = 0; i < WSZ; i++) {
      const double x = (double)(i - WSZ / 2);
      g[i] = exp(-(x * x) / (2.0 * 1.5 * 1.5));
      sum += g[i];
    }
    for (int i = 0; i < WSZ; i++) w.g[i] = (float)(g[i] / sum);
  }

  const float invN = 1.0f / (float)((double)in_sizes[0]);

  ssim_main_kernel<<<NBLOCKS, NTHREADS, 0, stream>>>(
      img1, img2, partials, w, planes, H, Wd, tilesX, tilesY, nTiles);
  ssim_final_kernel<<<1, NTHREADS, 0, stream>>>(partials, out, NBLOCKS, invN);
}

// Round 2
// 295.562 us; speedup vs baseline: 1.0547x; 1.0547x over previous
//
#include <hip/hip_runtime.h>
#include <math.h>

#define WSZ 11
#define PAD 5
#define TX 64
#define TY 32
#define IN_H (TY + 2 * PAD)   // 42
#define IN_W (TX + 2 * PAD)   // 74
#define RS   76               // raw row stride (floats), keeps rows 16B-aligned
#define TILES_X (512 / TX)    // 8
#define TILES_Y (512 / TY)    // 16
#define NTHREADS 256
#define NBLOCKS 2048

struct GW { float g[WSZ]; };

__device__ __forceinline__ void fma4(float4& a, float g, const float4& v) {
  a.x = fmaf(g, v.x, a.x); a.y = fmaf(g, v.y, a.y);
  a.z = fmaf(g, v.z, a.z); a.w = fmaf(g, v.w, a.w);
}

__device__ __forceinline__ float ssim_px(float m1, float m2, float m11,
                                         float m22, float m12) {
  const float C1 = 0.0001f, C2 = 0.0009f;
  const float mu1s = m1 * m1, mu2s = m2 * m2, mu12 = m1 * m2;
  const float num = (2.f * mu12 + C1) * (2.f * (m12 - mu12) + C2);
  const float den = (mu1s + mu2s + C1) * ((m11 - mu1s) + (m22 - mu2s) + C2);
  return num * __builtin_amdgcn_rcpf(den);
}

__global__ __launch_bounds__(NTHREADS, 2) void ssim_main_kernel(
    const float* __restrict__ img1, const float* __restrict__ img2,
    float* __restrict__ partials, GW w, int nTiles)
{
  __shared__ __align__(16) float s1[IN_H][RS];
  __shared__ __align__(16) float s2[IN_H][RS];
  __shared__ __align__(16) float si[5][IN_H][TX];  // horizontal-blurred fields
  __shared__ float sred[NTHREADS / 64];

  const int tid = threadIdx.x;
  float accSum = 0.f;

  for (int tile = blockIdx.x; tile < nTiles; tile += gridDim.x) {
    int t = tile;
    const int tx = t % TILES_X; t /= TILES_X;
    const int ty = t % TILES_Y; t /= TILES_Y;
    const float* __restrict__ p1 = img1 + (size_t)t * 512 * 512;
    const float* __restrict__ p2 = img2 + (size_t)t * 512 * 512;
    const int gx0 = tx * TX - PAD;
    const int gy0 = ty * TY - PAD;

    // ---- stage raw tiles (zero-padded at image borders) ----
    for (int i = tid; i < IN_H * IN_W; i += NTHREADS) {
      const int r = i / IN_W, c = i % IN_W;
      const int gy = gy0 + r, gx = gx0 + c;
      const bool ok = (gx >= 0) & (gx < 512) & (gy >= 0) & (gy < 512);
      const size_t idx = (size_t)gy * 512 + gx;
      s1[r][c] = ok ? p1[idx] : 0.f;
      s2[r][c] = ok ? p2[idx] : 0.f;
    }
    __syncthreads();

    // ---- horizontal pass: 4 outputs (one float4) per item ----
    // items: 42 rows x 16 x-groups = 672
    for (int i = tid; i < IN_H * (TX / 4); i += NTHREADS) {
      const int r = i / (TX / 4), j = i % (TX / 4);
      float a[16], b[16];
#pragma unroll
      for (int tq = 0; tq < 4; tq++) {
        const float4 v1 = *(const float4*)&s1[r][4 * j + 4 * tq];
        const float4 v2 = *(const float4*)&s2[r][4 * j + 4 * tq];
        a[4 * tq + 0] = v1.x; a[4 * tq + 1] = v1.y;
        a[4 * tq + 2] = v1.z; a[4 * tq + 3] = v1.w;
        b[4 * tq + 0] = v2.x; b[4 * tq + 1] = v2.y;
        b[4 * tq + 2] = v2.z; b[4 * tq + 3] = v2.w;
      }
      float aa[14], bb[14], ab[14];
#pragma unroll
      for (int p = 0; p < 14; p++) {
        aa[p] = a[p] * a[p]; bb[p] = b[p] * b[p]; ab[p] = a[p] * b[p];
      }
      float m1[4] = {0, 0, 0, 0}, m2[4] = {0, 0, 0, 0}, m11[4] = {0, 0, 0, 0},
            m22[4] = {0, 0, 0, 0}, m12[4] = {0, 0, 0, 0};
#pragma unroll
      for (int k = 0; k < WSZ; k++) {
        const float g = w.g[k];
#pragma unroll
        for (int x = 0; x < 4; x++) {
          m1[x]  = fmaf(g, a[x + k],  m1[x]);
          m2[x]  = fmaf(g, b[x + k],  m2[x]);
          m11[x] = fmaf(g, aa[x + k], m11[x]);
          m22[x] = fmaf(g, bb[x + k], m22[x]);
          m12[x] = fmaf(g, ab[x + k], m12[x]);
        }
      }
      const int jw = j ^ (r & 3);  // bank swizzle on float4 index
      *(float4*)&si[0][r][4 * jw] = make_float4(m1[0], m1[1], m1[2], m1[3]);
      *(float4*)&si[1][r][4 * jw] = make_float4(m2[0], m2[1], m2[2], m2[3]);
      *(float4*)&si[2][r][4 * jw] = make_float4(m11[0], m11[1], m11[2], m11[3]);
      *(float4*)&si[3][r][4 * jw] = make_float4(m22[0], m22[1], m22[2], m22[3]);
      *(float4*)&si[4][r][4 * jw] = make_float4(m12[0], m12[1], m12[2], m12[3]);
    }
    __syncthreads();

    // ---- vertical pass + SSIM: each thread does 4x x 2y (one item) ----
    // items: 16 x-groups x 16 y-groups = 256 == NTHREADS
    {
      const int yi = tid >> 4, j = tid & 15;
      const int y0 = 2 * yi;
      float4 acc0[5], acc1[5];
#pragma unroll
      for (int f = 0; f < 5; f++) {
        acc0[f] = make_float4(0, 0, 0, 0);
        acc1[f] = make_float4(0, 0, 0, 0);
      }
#pragma unroll
      for (int k = 0; k < WSZ + 1; k++) {
        const int rr = y0 + k;
        const int jw = j ^ (rr & 3);
#pragma unroll
        for (int f = 0; f < 5; f++) {
          const float4 v = *(const float4*)&si[f][rr][4 * jw];
          if (k < WSZ) fma4(acc0[f], w.g[k], v);
          if (k >= 1)  fma4(acc1[f], w.g[k - 1], v);
        }
      }
      accSum += ssim_px(acc0[0].x, acc0[1].x, acc0[2].x, acc0[3].x, acc0[4].x);
      accSum += ssim_px(acc0[0].y, acc0[1].y, acc0[2].y, acc0[3].y, acc0[4].y);
      accSum += ssim_px(acc0[0].z, acc0[1].z, acc0[2].z, acc0[3].z, acc0[4].z);
      accSum += ssim_px(acc0[0].w, acc0[1].w, acc0[2].w, acc0[3].w, acc0[4].w);
      accSum += ssim_px(acc1[0].x, acc1[1].x, acc1[2].x, acc1[3].x, acc1[4].x);
      accSum += ssim_px(acc1[0].y, acc1[1].y, acc1[2].y, acc1[3].y, acc1[4].y);
      accSum += ssim_px(acc1[0].z, acc1[1].z, acc1[2].z, acc1[3].z, acc1[4].z);
      accSum += ssim_px(acc1[0].w, acc1[1].w, acc1[2].w, acc1[3].w, acc1[4].w);
    }
    __syncthreads();  // protect LDS before next tile overwrites
  }

  // ---- block reduction ----
  for (int off = 32; off > 0; off >>= 1)
    accSum += __shfl_down(accSum, off, 64);
  if ((tid & 63) == 0) sred[tid >> 6] = accSum;
  __syncthreads();
  if (tid == 0) {
    float s = 0.f;
#pragma unroll
    for (int i = 0; i < NTHREADS / 64; i++) s += sred[i];
    partials[blockIdx.x] = s;
  }
}

__global__ __launch_bounds__(NTHREADS) void ssim_final_kernel(
    const float* __restrict__ partials, float* __restrict__ out,
    int n, double invN)
{
  __shared__ double sred[NTHREADS / 64];
  const int tid = threadIdx.x;
  double s = 0.0;
  for (int i = tid; i < n; i += NTHREADS) s += (double)partials[i];
  for (int off = 32; off > 0; off >>= 1)
    s += __shfl_down(s, off, 64);
  if ((tid & 63) == 0) sred[tid >> 6] = s;
  __syncthreads();
  if (tid == 0) {
    double tot = 0.0;
#pragma unroll
    for (int i = 0; i < NTHREADS / 64; i++) tot += sred[i];
    out[0] = (float)(1.0 - tot * invN);
  }
}

extern "C" void kernel_launch(void* const* d_in, const int* in_sizes, int n_in,
                              void* d_out, int out_size, void* d_ws, size_t ws_size,
                              hipStream_t stream) {
  const float* img1 = (const float*)d_in[0];
  const float* img2 = (const float*)d_in[1];
  float* out = (float*)d_out;
  float* partials = (float*)d_ws;

  const int planes = in_sizes[0] / (512 * 512);       // 96
  const int nTiles = planes * TILES_X * TILES_Y;      // 12288

  GW w;
  {
    double g[WSZ], sum = 0.0;
    for (int i = 0; i < WSZ; i++) {
      const double x = (double)(i - WSZ / 2);
      g[i] = exp(-(x * x) / (2.0 * 1.5 * 1.5));
      sum += g[i];
    }
    for (int i = 0; i < WSZ; i++) w.g[i] = (float)(g[i] / sum);
  }

  const double invN = 1.0 / (double)in_sizes[0];

  ssim_main_kernel<<<NBLOCKS, NTHREADS, 0, stream>>>(img1, img2, partials, w, nTiles);
  ssim_final_kernel<<<1, NTHREADS, 0, stream>>>(partials, out, NBLOCKS, invN);
}